// Round 1
// baseline (1237.219 us; speedup 1.0000x reference)
//
#include <hip/hip_runtime.h>
#include <hip/hip_bf16.h>
#include <cstdint>
#include <cstddef>

#define M_TOK 8192
#define K_IN  4096
#define N_OUT 4096

typedef __attribute__((ext_vector_type(8))) short short8;
typedef __attribute__((ext_vector_type(8))) unsigned short ushort8;
typedef __attribute__((ext_vector_type(4))) float f32x4;

// ---------- fp32 -> bf16 hi/lo split (RNE) ----------
__device__ inline void split_bf16(float x, unsigned short& h, unsigned short& l) {
    unsigned int u = __float_as_uint(x);
    unsigned int hb = (u + 0x7FFFu + ((u >> 16) & 1u)) >> 16;
    h = (unsigned short)hb;
    float hf = __uint_as_float(hb << 16);
    float r = x - hf;                       // exact (Sterbenz)
    unsigned int ur = __float_as_uint(r);
    unsigned int lb = (ur + 0x7FFFu + ((ur >> 16) & 1u)) >> 16;
    l = (unsigned short)lb;
}

// ---------- pre-pass: X -> Xhi/Xlo ----------
__global__ void sl_cvt_x(const float* __restrict__ X,
                         unsigned short* __restrict__ hi,
                         unsigned short* __restrict__ lo,
                         int ngroups) {
    int stride = gridDim.x * blockDim.x;
    for (int g = blockIdx.x * blockDim.x + threadIdx.x; g < ngroups; g += stride) {
        const float4* p = (const float4*)X + (size_t)g * 2;
        float4 a = p[0], b = p[1];
        float f[8] = {a.x, a.y, a.z, a.w, b.x, b.y, b.z, b.w};
        ushort8 h, l;
#pragma unroll
        for (int i = 0; i < 8; ++i) {
            unsigned short hh, ll;
            split_bf16(f[i], hh, ll);
            h[i] = hh; l[i] = ll;
        }
        *(ushort8*)(hi + (size_t)g * 8) = h;
        *(ushort8*)(lo + (size_t)g * 8) = l;
    }
}

// ---------- pre-pass: W*mask -> Whi/Wlo ----------
__global__ void sl_cvt_w(const float* __restrict__ W,
                         const int* __restrict__ mask,
                         unsigned short* __restrict__ hi,
                         unsigned short* __restrict__ lo,
                         int ngroups) {
    int stride = gridDim.x * blockDim.x;
    for (int g = blockIdx.x * blockDim.x + threadIdx.x; g < ngroups; g += stride) {
        const float4* p = (const float4*)W + (size_t)g * 2;
        const int4*  mp = (const int4*)mask + (size_t)g * 2;
        float4 a = p[0], b = p[1];
        int4 ma = mp[0], mb = mp[1];
        float f[8];
        f[0] = ma.x ? a.x : 0.f;  f[1] = ma.y ? a.y : 0.f;
        f[2] = ma.z ? a.z : 0.f;  f[3] = ma.w ? a.w : 0.f;
        f[4] = mb.x ? b.x : 0.f;  f[5] = mb.y ? b.y : 0.f;
        f[6] = mb.z ? b.z : 0.f;  f[7] = mb.w ? b.w : 0.f;
        ushort8 h, l;
#pragma unroll
        for (int i = 0; i < 8; ++i) {
            unsigned short hh, ll;
            split_bf16(f[i], hh, ll);
            h[i] = hh; l[i] = ll;
        }
        *(ushort8*)(hi + (size_t)g * 8) = h;
        *(ushort8*)(lo + (size_t)g * 8) = l;
    }
}

// ---------- async global -> LDS, 16B per lane ----------
__device__ inline void gload16(const void* g, void* l) {
    __builtin_amdgcn_global_load_lds(
        (const __attribute__((address_space(1))) void*)g,
        (__attribute__((address_space(3))) void*)l, 16, 0, 0);
}

// ---------- main GEMM: C = Xsplit @ Wsplit^T + b, BF16x3 ----------
// BM=BN=128, BK=32. LDS tile row layout: [hi 32 elems | lo 32 elems] = 128B/row,
// XOR-swizzled in 16B blocks: stored slot s of row r holds source kb = s ^ (r&7).
__global__ __launch_bounds__(256, 3)
void sl_gemm_bf16x3(const unsigned short* __restrict__ Xhi,
                    const unsigned short* __restrict__ Xlo,
                    const unsigned short* __restrict__ Whi,
                    const unsigned short* __restrict__ Wlo,
                    const float* __restrict__ bias,
                    float* __restrict__ out) {
    __shared__ __align__(16) unsigned short At[128 * 64];
    __shared__ __align__(16) unsigned short Bt[128 * 64];

    // XCD-aware bijective swizzle: nwg = 2048, 2048/8 = 256 per XCD
    const int bid = blockIdx.x;
    const int swz = (bid & 7) * 256 + (bid >> 3);
    const int bm = swz >> 5;          // 0..63  (M tiles)
    const int bn = swz & 31;          // 0..31  (N tiles)
    const int brow = bm * 128;
    const int bcol = bn * 128;

    const int tid = threadIdx.x;
    const int w   = tid >> 6;         // wave 0..3
    const int l   = tid & 63;
    const int wr  = w >> 1, wc = w & 1;

    // ---- staging setup (pre-swizzled global source, linear LDS dest) ----
    const int rlo  = l >> 3;          // row within 8-row segment (== row&7)
    const int slot = l & 7;           // 16B slot within 128B row
    const int kb   = slot ^ rlo;      // source block: 0..3 = hi, 4..7 = lo
    const unsigned short* aBase = (kb < 4) ? Xhi : Xlo;
    const unsigned short* bBase = (kb < 4) ? Whi : Wlo;
    const int kboff = (kb & 3) * 8;   // element offset within 32-elem k-chunk

    const unsigned short* aSrc[4];
    const unsigned short* bSrc[4];
#pragma unroll
    for (int i = 0; i < 4; ++i) {
        const int ar = brow + w * 32 + i * 8 + rlo;   // X row
        const int br = bcol + w * 32 + i * 8 + rlo;   // W row (out feature)
        aSrc[i] = aBase + (size_t)ar * K_IN + kboff;
        bSrc[i] = bBase + (size_t)br * K_IN + kboff;
    }

    const int lr = l & 15;            // fragment row/col selector
    const int kg = l >> 4;            // k-group 0..3

    f32x4 acc[4][4];
#pragma unroll
    for (int i = 0; i < 4; ++i)
#pragma unroll
        for (int j = 0; j < 4; ++j)
            acc[i][j] = (f32x4){0.f, 0.f, 0.f, 0.f};

    for (int kt = 0; kt < K_IN / 32; ++kt) {
        const int koff = kt * 32;
        // ---- stage A and B tiles (each wave: 4 segs of A, 4 of B) ----
#pragma unroll
        for (int i = 0; i < 4; ++i) {
            gload16(aSrc[i] + koff, (char*)At + (w * 4 + i) * 1024);
            gload16(bSrc[i] + koff, (char*)Bt + (w * 4 + i) * 1024);
        }
        __syncthreads();   // compiler emits vmcnt(0) drain before s_barrier

        // ---- fragments (XOR-swizzled ds_read_b128) + 48 MFMA ----
        short8 bhi[4], blo[4];
#pragma unroll
        for (int j = 0; j < 4; ++j) {
            const int rowB = wc * 64 + j * 16 + lr;
            const int sw = rowB & 7;
            bhi[j] = *(const short8*)(Bt + rowB * 64 + ((kg ^ sw) << 3));
            blo[j] = *(const short8*)(Bt + rowB * 64 + (((kg + 4) ^ sw) << 3));
        }
#pragma unroll
        for (int i = 0; i < 4; ++i) {
            const int rowA = wr * 64 + i * 16 + lr;
            const int sw = rowA & 7;
            short8 ahi = *(const short8*)(At + rowA * 64 + ((kg ^ sw) << 3));
            short8 alo = *(const short8*)(At + rowA * 64 + (((kg + 4) ^ sw) << 3));
#pragma unroll
            for (int j = 0; j < 4; ++j) {
                acc[i][j] = __builtin_amdgcn_mfma_f32_16x16x32_bf16(ahi, bhi[j], acc[i][j], 0, 0, 0);
                acc[i][j] = __builtin_amdgcn_mfma_f32_16x16x32_bf16(ahi, blo[j], acc[i][j], 0, 0, 0);
                acc[i][j] = __builtin_amdgcn_mfma_f32_16x16x32_bf16(alo, bhi[j], acc[i][j], 0, 0, 0);
            }
        }
        __syncthreads();
    }

    // ---- epilogue: C/D layout col=lane&15, row=(lane>>4)*4+reg ----
    float bv[4];
#pragma unroll
    for (int j = 0; j < 4; ++j)
        bv[j] = bias[bcol + wc * 64 + j * 16 + lr];
#pragma unroll
    for (int i = 0; i < 4; ++i) {
        const int trow = brow + wr * 64 + i * 16 + kg * 4;
#pragma unroll
        for (int j = 0; j < 4; ++j) {
            const int ocol = bcol + wc * 64 + j * 16 + lr;
#pragma unroll
            for (int r = 0; r < 4; ++r)
                out[(size_t)(trow + r) * N_OUT + ocol] = acc[i][j][r] + bv[j];
        }
    }
}

// ---------- correctness fallback if ws is too small ----------
__global__ void sl_naive(const float* __restrict__ X, const float* __restrict__ W,
                         const int* __restrict__ mask, const float* __restrict__ bias,
                         float* __restrict__ out) {
    int o = blockIdx.x * blockDim.x + threadIdx.x;
    int t = blockIdx.y;
    if (o >= N_OUT) return;
    const float* xr = X + (size_t)t * K_IN;
    const float* wr = W + (size_t)o * K_IN;
    const int*   mr = mask + (size_t)o * K_IN;
    float s = 0.f;
    for (int k = 0; k < K_IN; ++k)
        s += xr[k] * (mr[k] ? wr[k] : 0.f);
    out[(size_t)t * N_OUT + o] = s + bias[o];
}

extern "C" void kernel_launch(void* const* d_in, const int* in_sizes, int n_in,
                              void* d_out, int out_size, void* d_ws, size_t ws_size,
                              hipStream_t stream) {
    (void)in_sizes; (void)n_in; (void)out_size;
    const float* X    = (const float*)d_in[0];
    const float* W    = (const float*)d_in[1];
    const int*   mask = (const int*)d_in[2];
    const float* bias = (const float*)d_in[3];
    float* out = (float*)d_out;

    const size_t xplane = (size_t)M_TOK * K_IN;   // elements per X plane
    const size_t wplane = (size_t)N_OUT * K_IN;
    const size_t need = (2 * xplane + 2 * wplane) * sizeof(unsigned short); // 201,326,592 B

    if (ws_size < need) {
        dim3 g((N_OUT + 255) / 256, M_TOK);
        sl_naive<<<g, 256, 0, stream>>>(X, W, mask, bias, out);
        return;
    }

    unsigned short* Xhi = (unsigned short*)d_ws;
    unsigned short* Xlo = Xhi + xplane;
    unsigned short* Whi = Xlo + xplane;
    unsigned short* Wlo = Whi + wplane;

    sl_cvt_x<<<2048, 256, 0, stream>>>(X, Xhi, Xlo, (int)(xplane / 8));
    sl_cvt_w<<<2048, 256, 0, stream>>>(W, mask, Whi, Wlo, (int)(wplane / 8));
    sl_gemm_bf16x3<<<2048, 256, 0, stream>>>(Xhi, Xlo, Whi, Wlo, bias, out);
}

// Round 2
// 1138.667 us; speedup vs baseline: 1.0866x; 1.0866x over previous
//
#include <hip/hip_runtime.h>
#include <hip/hip_bf16.h>
#include <cstdint>
#include <cstddef>

#define M_TOK 8192
#define K_IN  4096
#define N_OUT 4096
#define NKS   384      // 3 segments * (4096/32) K-subtiles

typedef __attribute__((ext_vector_type(8))) short short8;
typedef __attribute__((ext_vector_type(4))) unsigned short ushort4v;
typedef __attribute__((ext_vector_type(4))) float f32x4;

// ---------- fp32 -> bf16 hi/lo split (RNE) ----------
__device__ inline void split_bf16(float x, unsigned short& h, unsigned short& l) {
    unsigned int u = __float_as_uint(x);
    unsigned int hb = (u + 0x7FFFu + ((u >> 16) & 1u)) >> 16;
    h = (unsigned short)hb;
    float hf = __uint_as_float(hb << 16);
    float r = x - hf;                       // exact (Sterbenz)
    unsigned int ur = __float_as_uint(r);
    unsigned int lb = (ur + 0x7FFFu + ((ur >> 16) & 1u)) >> 16;
    l = (unsigned short)lb;
}

// ---------- pre-pass: X -> Xhi/Xlo (16B coalesced read, 8B+8B writes) ----------
__global__ __launch_bounds__(256) void sl_cvt_x(const float* __restrict__ X,
                                                unsigned short* __restrict__ hi,
                                                unsigned short* __restrict__ lo, int n4) {
    int stride = gridDim.x * blockDim.x;
    for (int g = blockIdx.x * blockDim.x + threadIdx.x; g < n4; g += stride) {
        float4 v = ((const float4*)X)[g];
        float f[4] = {v.x, v.y, v.z, v.w};
        ushort4v h, l;
#pragma unroll
        for (int i = 0; i < 4; ++i) {
            unsigned short hh, ll;
            split_bf16(f[i], hh, ll);
            h[i] = hh; l[i] = ll;
        }
        ((ushort4v*)hi)[g] = h;
        ((ushort4v*)lo)[g] = l;
    }
}

// ---------- pre-pass: W*mask -> Whi/Wlo ----------
__global__ __launch_bounds__(256) void sl_cvt_w(const float* __restrict__ W,
                                                const int* __restrict__ mask,
                                                unsigned short* __restrict__ hi,
                                                unsigned short* __restrict__ lo, int n4) {
    int stride = gridDim.x * blockDim.x;
    for (int g = blockIdx.x * blockDim.x + threadIdx.x; g < n4; g += stride) {
        float4 v = ((const float4*)W)[g];
        int4  mm = ((const int4*)mask)[g];
        float f[4];
        f[0] = mm.x ? v.x : 0.f;  f[1] = mm.y ? v.y : 0.f;
        f[2] = mm.z ? v.z : 0.f;  f[3] = mm.w ? v.w : 0.f;
        ushort4v h, l;
#pragma unroll
        for (int i = 0; i < 4; ++i) {
            unsigned short hh, ll;
            split_bf16(f[i], hh, ll);
            h[i] = hh; l[i] = ll;
        }
        ((ushort4v*)hi)[g] = h;
        ((ushort4v*)lo)[g] = l;
    }
}

// ---------- async global -> LDS, 16B per lane, wave-uniform dest base ----------
__device__ inline void gload16(const void* g, void* l) {
    __builtin_amdgcn_global_load_lds(
        (const __attribute__((address_space(1))) void*)g,
        (__attribute__((address_space(3))) void*)l, 16, 0, 0);
}

// =====================================================================
// Deep-pipelined 256x256 GEMM over virtual K' = 3*K (BF16x3 emulation).
//   seg 0: Xhi*Whi   seg 1: Xlo*Whi   seg 2: Xhi*Wlo
// 4-deep K-subtile (32-K) ring in LDS; counted vmcnt(8); 1 barrier/subtile.
// LDS swizzle: stored 16B-slot s' of row r holds source k-slot s'^((r>>1)&3).
// =====================================================================
__global__ __launch_bounds__(512, 2)
void sl_gemm_bf16x3(const unsigned short* __restrict__ Xhi,
                    const unsigned short* __restrict__ Xlo,
                    const unsigned short* __restrict__ Whi,
                    const unsigned short* __restrict__ Wlo,
                    const float* __restrict__ bias,
                    float* __restrict__ out) {
    __shared__ __align__(16) unsigned short As[4][256][32];   // 64 KiB
    __shared__ __align__(16) unsigned short Bs[4][256][32];   // 64 KiB

    // XCD-aware bijective swizzle: nwg = 512, q = 64
    const int bid = blockIdx.x;
    const int swz = (bid & 7) * 64 + (bid >> 3);
    const int bm = swz >> 4;              // 0..31
    const int bn = swz & 15;              // 0..15
    const int brow = bm * 256;
    const int bcol = bn * 256;

    const int tid = threadIdx.x;
    const int w   = tid >> 6;             // wave 0..7
    const int wm  = w >> 2, wn = w & 3;   // 2M x 4N wave grid
    const int l   = tid & 63;
    const int r   = l & 15;               // frag row selector
    const int kg  = l >> 4;               // k-group 0..3

    // ---- staging source offsets (pre-swizzled, element units) ----
    const int swzCol = (((tid & 3) ^ ((tid >> 3) & 3)) * 8);
    const size_t aRow0 = (size_t)(brow + (tid >> 2)) * K_IN + swzCol;
    const size_t aRow1 = aRow0 + (size_t)128 * K_IN;
    const size_t bRow0 = (size_t)(bcol + (tid >> 2)) * K_IN + swzCol;
    const size_t bRow1 = bRow0 + (size_t)128 * K_IN;

    char* AsB = (char*)&As[0][0][0];
    char* BsB = (char*)&Bs[0][0][0];
    const int woff = w * 1024;            // wave-uniform LDS dest base

    // ---- fragment read offsets (element units; 8192 elems per ring slot) ----
    const unsigned short* AsE = &As[0][0][0];
    const unsigned short* BsE = &Bs[0][0][0];
    const int slotOff = (kg ^ ((r >> 1) & 3)) * 8;
    const int aBaseE = (wm * 128 + r) * 32 + slotOff;
    const int bBaseE = (wn * 64 + r) * 32 + slotOff;

    f32x4 acc[8][4];
#pragma unroll
    for (int m = 0; m < 8; ++m)
#pragma unroll
        for (int n = 0; n < 4; ++n)
            acc[m][n] = (f32x4){0.f, 0.f, 0.f, 0.f};

#define STAGE_A(s_) do {                                                   \
    const int seg_ = (s_) >> 7;                                            \
    const unsigned short* pA_ = (seg_ == 1) ? Xlo : Xhi;                   \
    const size_t k_ = (size_t)((s_) & 127) * 32;                           \
    char* d_ = AsB + ((s_) & 3) * 16384 + woff;                            \
    gload16(pA_ + aRow0 + k_, d_);                                         \
    gload16(pA_ + aRow1 + k_, d_ + 8192);                                  \
} while (0)

#define STAGE_B(s_) do {                                                   \
    const int seg_ = (s_) >> 7;                                            \
    const unsigned short* pB_ = (seg_ == 2) ? Wlo : Whi;                   \
    const size_t k_ = (size_t)((s_) & 127) * 32;                           \
    char* d_ = BsB + ((s_) & 3) * 16384 + woff;                            \
    gload16(pB_ + bRow0 + k_, d_);                                         \
    gload16(pB_ + bRow1 + k_, d_ + 8192);                                  \
} while (0)

    // prologue: subtiles 0,1,2 in flight (12 loads)
    STAGE_A(0); STAGE_B(0);
    STAGE_A(1); STAGE_B(1);
    STAGE_A(2); STAGE_B(2);

    for (int s = 0; s < NKS; ++s) {
        // wait: <=8 outstanding (subtiles s+1, s+2) => subtile s landed
        asm volatile("s_waitcnt vmcnt(8)" ::: "memory");
        __builtin_amdgcn_s_barrier();
        __builtin_amdgcn_sched_barrier(0);

        const int buf = (s & 3) * 8192;
        const bool st = (s + 3) < NKS;
        if (st) STAGE_A(s + 3);

        short8 a[4], b[4];
#pragma unroll
        for (int n = 0; n < 4; ++n)
            b[n] = *(const short8*)(BsE + buf + bBaseE + n * 512);
#pragma unroll
        for (int m = 0; m < 4; ++m)
            a[m] = *(const short8*)(AsE + buf + aBaseE + m * 512);

        __builtin_amdgcn_s_setprio(1);
#pragma unroll
        for (int m = 0; m < 4; ++m)
#pragma unroll
            for (int n = 0; n < 4; ++n)
                acc[m][n] = __builtin_amdgcn_mfma_f32_16x16x32_bf16(a[m], b[n], acc[m][n], 0, 0, 0);
        __builtin_amdgcn_s_setprio(0);

        if (st) STAGE_B(s + 3);
#pragma unroll
        for (int m = 0; m < 4; ++m)
            a[m] = *(const short8*)(AsE + buf + aBaseE + (m + 4) * 512);

        __builtin_amdgcn_s_setprio(1);
#pragma unroll
        for (int m = 0; m < 4; ++m)
#pragma unroll
            for (int n = 0; n < 4; ++n)
                acc[m + 4][n] = __builtin_amdgcn_mfma_f32_16x16x32_bf16(a[m], b[n], acc[m + 4][n], 0, 0, 0);
        __builtin_amdgcn_s_setprio(0);
    }
#undef STAGE_A
#undef STAGE_B

    // ---- epilogue: C/D layout col=lane&15, row=(lane>>4)*4+reg ----
    float bv[4];
#pragma unroll
    for (int n = 0; n < 4; ++n)
        bv[n] = bias[bcol + wn * 64 + n * 16 + r];
    const int colBase = bcol + wn * 64 + r;
#pragma unroll
    for (int m = 0; m < 8; ++m) {
        const size_t rowb = (size_t)(brow + wm * 128 + m * 16 + kg * 4);
#pragma unroll
        for (int n = 0; n < 4; ++n) {
            const size_t c = (size_t)(colBase + n * 16);
#pragma unroll
            for (int q = 0; q < 4; ++q)
                out[(rowb + q) * N_OUT + c] = acc[m][n][q] + bv[n];
        }
    }
}

// ---------- correctness fallback if ws is too small ----------
__global__ void sl_naive(const float* __restrict__ X, const float* __restrict__ W,
                         const int* __restrict__ mask, const float* __restrict__ bias,
                         float* __restrict__ out) {
    int o = blockIdx.x * blockDim.x + threadIdx.x;
    int t = blockIdx.y;
    if (o >= N_OUT) return;
    const float* xr = X + (size_t)t * K_IN;
    const float* wr = W + (size_t)o * K_IN;
    const int*   mr = mask + (size_t)o * K_IN;
    float s = 0.f;
    for (int k = 0; k < K_IN; ++k)
        s += xr[k] * (mr[k] ? wr[k] : 0.f);
    out[(size_t)t * N_OUT + o] = s + bias[o];
}

extern "C" void kernel_launch(void* const* d_in, const int* in_sizes, int n_in,
                              void* d_out, int out_size, void* d_ws, size_t ws_size,
                              hipStream_t stream) {
    (void)in_sizes; (void)n_in; (void)out_size;
    const float* X    = (const float*)d_in[0];
    const float* W    = (const float*)d_in[1];
    const int*   mask = (const int*)d_in[2];
    const float* bias = (const float*)d_in[3];
    float* out = (float*)d_out;

    const size_t xplane = (size_t)M_TOK * K_IN;
    const size_t wplane = (size_t)N_OUT * K_IN;
    const size_t need = (2 * xplane + 2 * wplane) * sizeof(unsigned short);

    if (ws_size < need) {
        dim3 g((N_OUT + 255) / 256, M_TOK);
        sl_naive<<<g, 256, 0, stream>>>(X, W, mask, bias, out);
        return;
    }

    unsigned short* Xhi = (unsigned short*)d_ws;
    unsigned short* Xlo = Xhi + xplane;
    unsigned short* Whi = Xlo + xplane;
    unsigned short* Wlo = Whi + wplane;

    sl_cvt_x<<<2048, 256, 0, stream>>>(X, Xhi, Xlo, (int)(xplane / 4));
    sl_cvt_w<<<2048, 256, 0, stream>>>(W, mask, Whi, Wlo, (int)(wplane / 4));
    sl_gemm_bf16x3<<<512, 512, 0, stream>>>(Xhi, Xlo, Whi, Wlo, bias, out);
}

// Round 6
// 1110.857 us; speedup vs baseline: 1.1138x; 1.0250x over previous
//
#include <hip/hip_runtime.h>
#include <hip/hip_bf16.h>
#include <cstdint>
#include <cstddef>

#define M_TOK 8192
#define K_IN  4096
#define N_OUT 4096
#define NKS   384      // 3 segments * (4096/32) K-subtiles

typedef __attribute__((ext_vector_type(8))) short short8;
typedef __attribute__((ext_vector_type(8))) unsigned short ushort8;
typedef __attribute__((ext_vector_type(4))) float f32x4;

// ---------- fp32 -> bf16 hi/lo split (RNE) ----------
__device__ inline void split_bf16(float x, unsigned short& h, unsigned short& l) {
    unsigned int u = __float_as_uint(x);
    unsigned int hb = (u + 0x7FFFu + ((u >> 16) & 1u)) >> 16;
    h = (unsigned short)hb;
    float hf = __uint_as_float(hb << 16);
    float r = x - hf;                       // exact (Sterbenz)
    unsigned int ur = __float_as_uint(r);
    unsigned int lb = (ur + 0x7FFFu + ((ur >> 16) & 1u)) >> 16;
    l = (unsigned short)lb;
}

// ---------- fused pre-pass: X and W*mask -> bf16 hi/lo planes ----------
// blocks [0,2048): X (8 elems/thread/iter); [2048,4096): W+mask
__global__ __launch_bounds__(256) void sl_cvt_fused(const float* __restrict__ X,
                                                    const float* __restrict__ W,
                                                    const int* __restrict__ mask,
                                                    unsigned short* __restrict__ Xhi,
                                                    unsigned short* __restrict__ Xlo,
                                                    unsigned short* __restrict__ Whi,
                                                    unsigned short* __restrict__ Wlo) {
    const int b = blockIdx.x;
    if (b < 2048) {
        const int n8 = (M_TOK * K_IN) / 8;
        const int stride = 2048 * 256;
        for (int g = b * 256 + threadIdx.x; g < n8; g += stride) {
            float4 v0 = ((const float4*)X)[(size_t)g * 2];
            float4 v1 = ((const float4*)X)[(size_t)g * 2 + 1];
            float f[8] = {v0.x, v0.y, v0.z, v0.w, v1.x, v1.y, v1.z, v1.w};
            ushort8 h, l;
#pragma unroll
            for (int i = 0; i < 8; ++i) {
                unsigned short hh, ll;
                split_bf16(f[i], hh, ll);
                h[i] = hh; l[i] = ll;
            }
            *(ushort8*)(Xhi + (size_t)g * 8) = h;
            *(ushort8*)(Xlo + (size_t)g * 8) = l;
        }
    } else {
        const int n8 = (N_OUT * K_IN) / 8;
        const int stride = 2048 * 256;
        for (int g = (b - 2048) * 256 + threadIdx.x; g < n8; g += stride) {
            float4 v0 = ((const float4*)W)[(size_t)g * 2];
            float4 v1 = ((const float4*)W)[(size_t)g * 2 + 1];
            int4 m0 = ((const int4*)mask)[(size_t)g * 2];
            int4 m1 = ((const int4*)mask)[(size_t)g * 2 + 1];
            float f[8];
            f[0] = m0.x ? v0.x : 0.f;  f[1] = m0.y ? v0.y : 0.f;
            f[2] = m0.z ? v0.z : 0.f;  f[3] = m0.w ? v0.w : 0.f;
            f[4] = m1.x ? v1.x : 0.f;  f[5] = m1.y ? v1.y : 0.f;
            f[6] = m1.z ? v1.z : 0.f;  f[7] = m1.w ? v1.w : 0.f;
            ushort8 h, l;
#pragma unroll
            for (int i = 0; i < 8; ++i) {
                unsigned short hh, ll;
                split_bf16(f[i], hh, ll);
                h[i] = hh; l[i] = ll;
            }
            *(ushort8*)(Whi + (size_t)g * 8) = h;
            *(ushort8*)(Wlo + (size_t)g * 8) = l;
        }
    }
}

// ---------- async global -> LDS, 16B per lane, wave-uniform dest base ----------
__device__ inline void gload16(const void* g, void* l) {
    __builtin_amdgcn_global_load_lds(
        (const __attribute__((address_space(1))) void*)g,
        (__attribute__((address_space(3))) void*)l, 16, 0, 0);
}

// =====================================================================
// Phase-split 256x256 GEMM over virtual K' = 3*K (BF16x3 emulation).
//   seg 0: Xhi*Whi   seg 1: Xlo*Whi   seg 2: Xhi*Wlo
// 4-deep 32-K ring in LDS. Per subtile: 2 phases, each
//   [ds_reads ; stage half-tile ; (vmcnt in P2) ; barrier ; lgkmcnt(0) ;
//    setprio1 ; 16 MFMA ; setprio0 ; barrier]
// Counted vmcnt(8) once per subtile (drain only in 3-subtile tail).
// =====================================================================
__global__ __launch_bounds__(512, 2)
void sl_gemm_bf16x3(const unsigned short* __restrict__ Xhi,
                    const unsigned short* __restrict__ Xlo,
                    const unsigned short* __restrict__ Whi,
                    const unsigned short* __restrict__ Wlo,
                    const float* __restrict__ bias,
                    float* __restrict__ out) {
    __shared__ __align__(16) unsigned short As[4][256][32];   // 64 KiB
    __shared__ __align__(16) unsigned short Bs[4][256][32];   // 64 KiB

    // XCD-aware bijective swizzle: nwg = 512, 64 per XCD
    const int bid = blockIdx.x;
    const int swz = (bid & 7) * 64 + (bid >> 3);
    const int bm = swz >> 4;              // 0..31
    const int bn = swz & 15;              // 0..15
    const int brow = bm * 256;
    const int bcol = bn * 256;

    const int tid = threadIdx.x;
    const int w   = tid >> 6;             // wave 0..7
    const int wm  = w >> 2, wn = w & 3;   // 2M x 4N wave grid
    const int l   = tid & 63;
    const int r   = l & 15;               // frag row selector
    const int kg  = l >> 4;               // k-group 0..3

    // ---- staging source offsets (pre-swizzled, element units) ----
    const int swzCol = (((tid & 3) ^ ((tid >> 3) & 3)) * 8);
    const size_t aRow0 = (size_t)(brow + (tid >> 2)) * K_IN + swzCol;
    const size_t aRow1 = aRow0 + (size_t)128 * K_IN;
    const size_t bRow0 = (size_t)(bcol + (tid >> 2)) * K_IN + swzCol;
    const size_t bRow1 = bRow0 + (size_t)128 * K_IN;

    char* AsB = (char*)&As[0][0][0];
    char* BsB = (char*)&Bs[0][0][0];
    const int woff = w * 1024;            // wave-uniform LDS dest base

    // ---- fragment read offsets (element units; 8192 elems per ring slot) ----
    const unsigned short* AsE = &As[0][0][0];
    const unsigned short* BsE = &Bs[0][0][0];
    const int slotOff = (kg ^ ((r >> 1) & 3)) * 8;
    const int aBaseE = (wm * 128 + r) * 32 + slotOff;
    const int bBaseE = (wn * 64 + r) * 32 + slotOff;

    f32x4 acc[8][4];
#pragma unroll
    for (int m = 0; m < 8; ++m)
#pragma unroll
        for (int n = 0; n < 4; ++n)
            acc[m][n] = (f32x4){0.f, 0.f, 0.f, 0.f};

#define STAGE_A(s_) do {                                                   \
    const int seg_ = (s_) >> 7;                                            \
    const unsigned short* pA_ = (seg_ == 1) ? Xlo : Xhi;                   \
    const size_t k_ = (size_t)((s_) & 127) * 32;                           \
    char* d_ = AsB + ((s_) & 3) * 16384 + woff;                            \
    gload16(pA_ + aRow0 + k_, d_);                                         \
    gload16(pA_ + aRow1 + k_, d_ + 8192);                                  \
} while (0)

#define STAGE_B(s_) do {                                                   \
    const int seg_ = (s_) >> 7;                                            \
    const unsigned short* pB_ = (seg_ == 2) ? Wlo : Whi;                   \
    const size_t k_ = (size_t)((s_) & 127) * 32;                           \
    char* d_ = BsB + ((s_) & 3) * 16384 + woff;                            \
    gload16(pB_ + bRow0 + k_, d_);                                         \
    gload16(pB_ + bRow1 + k_, d_ + 8192);                                  \
} while (0)

    // prologue: subtiles 0,1,2 in flight (12 loads); ensure subtile 0 landed
    STAGE_A(0); STAGE_B(0);
    STAGE_A(1); STAGE_B(1);
    STAGE_A(2); STAGE_B(2);
    asm volatile("s_waitcnt vmcnt(8)" ::: "memory");
    __builtin_amdgcn_s_barrier();
    __builtin_amdgcn_sched_barrier(0);

    for (int s = 0; s < NKS; ++s) {
        const int buf = (s & 3) * 8192;
        const bool st = (s + 3) < NKS;

        // ================= Phase 1: b[0..3], a[0..3]; MFMA m0-3 =================
        short8 b0 = *(const short8*)(BsE + buf + bBaseE);
        short8 b1 = *(const short8*)(BsE + buf + bBaseE + 512);
        short8 b2 = *(const short8*)(BsE + buf + bBaseE + 1024);
        short8 b3 = *(const short8*)(BsE + buf + bBaseE + 1536);
        short8 p0 = *(const short8*)(AsE + buf + aBaseE);
        short8 p1 = *(const short8*)(AsE + buf + aBaseE + 512);
        short8 p2 = *(const short8*)(AsE + buf + aBaseE + 1024);
        short8 p3 = *(const short8*)(AsE + buf + aBaseE + 1536);
        if (st) STAGE_A(s + 3);

        __builtin_amdgcn_s_barrier();
        asm volatile("s_waitcnt lgkmcnt(0)" ::: "memory");
        __builtin_amdgcn_sched_barrier(0);
        __builtin_amdgcn_s_setprio(1);
        acc[0][0] = __builtin_amdgcn_mfma_f32_16x16x32_bf16(p0, b0, acc[0][0], 0, 0, 0);
        acc[0][1] = __builtin_amdgcn_mfma_f32_16x16x32_bf16(p0, b1, acc[0][1], 0, 0, 0);
        acc[0][2] = __builtin_amdgcn_mfma_f32_16x16x32_bf16(p0, b2, acc[0][2], 0, 0, 0);
        acc[0][3] = __builtin_amdgcn_mfma_f32_16x16x32_bf16(p0, b3, acc[0][3], 0, 0, 0);
        acc[1][0] = __builtin_amdgcn_mfma_f32_16x16x32_bf16(p1, b0, acc[1][0], 0, 0, 0);
        acc[1][1] = __builtin_amdgcn_mfma_f32_16x16x32_bf16(p1, b1, acc[1][1], 0, 0, 0);
        acc[1][2] = __builtin_amdgcn_mfma_f32_16x16x32_bf16(p1, b2, acc[1][2], 0, 0, 0);
        acc[1][3] = __builtin_amdgcn_mfma_f32_16x16x32_bf16(p1, b3, acc[1][3], 0, 0, 0);
        acc[2][0] = __builtin_amdgcn_mfma_f32_16x16x32_bf16(p2, b0, acc[2][0], 0, 0, 0);
        acc[2][1] = __builtin_amdgcn_mfma_f32_16x16x32_bf16(p2, b1, acc[2][1], 0, 0, 0);
        acc[2][2] = __builtin_amdgcn_mfma_f32_16x16x32_bf16(p2, b2, acc[2][2], 0, 0, 0);
        acc[2][3] = __builtin_amdgcn_mfma_f32_16x16x32_bf16(p2, b3, acc[2][3], 0, 0, 0);
        acc[3][0] = __builtin_amdgcn_mfma_f32_16x16x32_bf16(p3, b0, acc[3][0], 0, 0, 0);
        acc[3][1] = __builtin_amdgcn_mfma_f32_16x16x32_bf16(p3, b1, acc[3][1], 0, 0, 0);
        acc[3][2] = __builtin_amdgcn_mfma_f32_16x16x32_bf16(p3, b2, acc[3][2], 0, 0, 0);
        acc[3][3] = __builtin_amdgcn_mfma_f32_16x16x32_bf16(p3, b3, acc[3][3], 0, 0, 0);
        __builtin_amdgcn_s_setprio(0);
        __builtin_amdgcn_s_barrier();
        __builtin_amdgcn_sched_barrier(0);

        // ================= Phase 2: a[4..7]; MFMA m4-7 =================
        short8 q0 = *(const short8*)(AsE + buf + aBaseE + 2048);
        short8 q1 = *(const short8*)(AsE + buf + aBaseE + 2560);
        short8 q2 = *(const short8*)(AsE + buf + aBaseE + 3072);
        short8 q3 = *(const short8*)(AsE + buf + aBaseE + 3584);
        if (st) {
            STAGE_B(s + 3);
            asm volatile("s_waitcnt vmcnt(8)" ::: "memory");
        } else {
            asm volatile("s_waitcnt vmcnt(0)" ::: "memory");
        }

        __builtin_amdgcn_s_barrier();
        asm volatile("s_waitcnt lgkmcnt(0)" ::: "memory");
        __builtin_amdgcn_sched_barrier(0);
        __builtin_amdgcn_s_setprio(1);
        acc[4][0] = __builtin_amdgcn_mfma_f32_16x16x32_bf16(q0, b0, acc[4][0], 0, 0, 0);
        acc[4][1] = __builtin_amdgcn_mfma_f32_16x16x32_bf16(q0, b1, acc[4][1], 0, 0, 0);
        acc[4][2] = __builtin_amdgcn_mfma_f32_16x16x32_bf16(q0, b2, acc[4][2], 0, 0, 0);
        acc[4][3] = __builtin_amdgcn_mfma_f32_16x16x32_bf16(q0, b3, acc[4][3], 0, 0, 0);
        acc[5][0] = __builtin_amdgcn_mfma_f32_16x16x32_bf16(q1, b0, acc[5][0], 0, 0, 0);
        acc[5][1] = __builtin_amdgcn_mfma_f32_16x16x32_bf16(q1, b1, acc[5][1], 0, 0, 0);
        acc[5][2] = __builtin_amdgcn_mfma_f32_16x16x32_bf16(q1, b2, acc[5][2], 0, 0, 0);
        acc[5][3] = __builtin_amdgcn_mfma_f32_16x16x32_bf16(q1, b3, acc[5][3], 0, 0, 0);
        acc[6][0] = __builtin_amdgcn_mfma_f32_16x16x32_bf16(q2, b0, acc[6][0], 0, 0, 0);
        acc[6][1] = __builtin_amdgcn_mfma_f32_16x16x32_bf16(q2, b1, acc[6][1], 0, 0, 0);
        acc[6][2] = __builtin_amdgcn_mfma_f32_16x16x32_bf16(q2, b2, acc[6][2], 0, 0, 0);
        acc[6][3] = __builtin_amdgcn_mfma_f32_16x16x32_bf16(q2, b3, acc[6][3], 0, 0, 0);
        acc[7][0] = __builtin_amdgcn_mfma_f32_16x16x32_bf16(q3, b0, acc[7][0], 0, 0, 0);
        acc[7][1] = __builtin_amdgcn_mfma_f32_16x16x32_bf16(q3, b1, acc[7][1], 0, 0, 0);
        acc[7][2] = __builtin_amdgcn_mfma_f32_16x16x32_bf16(q3, b2, acc[7][2], 0, 0, 0);
        acc[7][3] = __builtin_amdgcn_mfma_f32_16x16x32_bf16(q3, b3, acc[7][3], 0, 0, 0);
        __builtin_amdgcn_s_setprio(0);
        __builtin_amdgcn_s_barrier();
        __builtin_amdgcn_sched_barrier(0);
    }
#undef STAGE_A
#undef STAGE_B

    // ---- epilogue: C/D layout col=lane&15, row=(lane>>4)*4+reg ----
    float bv[4];
#pragma unroll
    for (int n = 0; n < 4; ++n)
        bv[n] = bias[bcol + wn * 64 + n * 16 + r];
    const int colBase = bcol + wn * 64 + r;
#pragma unroll
    for (int m = 0; m < 8; ++m) {
        const size_t rowb = (size_t)(brow + wm * 128 + m * 16 + kg * 4);
#pragma unroll
        for (int n = 0; n < 4; ++n) {
            const size_t c = (size_t)(colBase + n * 16);
#pragma unroll
            for (int q = 0; q < 4; ++q)
                out[(rowb + q) * N_OUT + c] = acc[m][n][q] + bv[n];
        }
    }
}

// ---------- correctness fallback if ws is too small ----------
__global__ void sl_naive(const float* __restrict__ X, const float* __restrict__ W,
                         const int* __restrict__ mask, const float* __restrict__ bias,
                         float* __restrict__ out) {
    int o = blockIdx.x * blockDim.x + threadIdx.x;
    int t = blockIdx.y;
    if (o >= N_OUT) return;
    const float* xr = X + (size_t)t * K_IN;
    const float* wr = W + (size_t)o * K_IN;
    const int*   mr = mask + (size_t)o * K_IN;
    float s = 0.f;
    for (int k = 0; k < K_IN; ++k)
        s += xr[k] * (mr[k] ? wr[k] : 0.f);
    out[(size_t)t * N_OUT + o] = s + bias[o];
}

extern "C" void kernel_launch(void* const* d_in, const int* in_sizes, int n_in,
                              void* d_out, int out_size, void* d_ws, size_t ws_size,
                              hipStream_t stream) {
    (void)in_sizes; (void)n_in; (void)out_size;
    const float* X    = (const float*)d_in[0];
    const float* W    = (const float*)d_in[1];
    const int*   mask = (const int*)d_in[2];
    const float* bias = (const float*)d_in[3];
    float* out = (float*)d_out;

    const size_t xplane = (size_t)M_TOK * K_IN;
    const size_t wplane = (size_t)N_OUT * K_IN;
    const size_t need = (2 * xplane + 2 * wplane) * sizeof(unsigned short);

    if (ws_size < need) {
        dim3 g((N_OUT + 255) / 256, M_TOK);
        sl_naive<<<g, 256, 0, stream>>>(X, W, mask, bias, out);
        return;
    }

    unsigned short* Xhi = (unsigned short*)d_ws;
    unsigned short* Xlo = Xhi + xplane;
    unsigned short* Whi = Xlo + xplane;
    unsigned short* Wlo = Whi + wplane;

    sl_cvt_fused<<<4096, 256, 0, stream>>>(X, W, mask, Xhi, Xlo, Whi, Wlo);
    sl_gemm_bf16x3<<<512, 512, 0, stream>>>(Xhi, Xlo, Whi, Wlo, bias, out);
}